// Round 1
// baseline (194.272 us; speedup 1.0000x reference)
//
#include <hip/hip_runtime.h>
#include <hip/hip_bf16.h>
#include <math.h>

// YOLO decode + hard NMS, exact equivalent of the JAX reference.
// R7: k_nms widened 64 -> 256 threads. Bitonic sort replaced by rank sort
// (unique keys -> unique ranks), pre-test parallelized across 256 candidates,
// accept loop on wave 0 with 4 register-resident candidates per lane.
// All arithmetic expressions/orders identical to R6 (absmax 0.0 preserved).

#define NCLS  80
#define MAXB  100
#define N0    6912     // 48*48*3
#define N1    27648    // 96*96*3
#define NTOT  145152
#define NTILE 2268     // 64-box tiles
#define NB    4096     // histogram bins (linear in score)
#define CAP   2048     // global candidate capacity
#define CAPL  2048     // nms LDS key capacity (fallback)
#define CHUNK 256      // target chunk size for nms sort+sweep
#define TBLK  256      // k_nms block size
#define NEGF  -3.402823466e38f
#define POSF   3.402823466e38f

// ws layout (bytes), ~0.8 MB
#define WS_CONF 0
#define WS_SCAL (NTOT * 4)
#define WS_PART (WS_SCAL + 16)
#define WS_HIST (WS_PART + NTILE * 16)       // 8 shards * NB ints
#define WS_BINC (WS_HIST + 8 * NB * 4)       // NB ints (contiguous after HIST)
#define WS_SUF  (WS_BINC + NB * 4)
#define WS_META (WS_SUF + (NB + 2) * 4)
#define WS_CAND (WS_META + 16)

// Bin index; identical expression everywhere -> identical rounding.
__device__ __forceinline__ int binOf(float s, float Smax) {
    int b = (int)((s / Smax) * (float)NB);
    return b > (NB - 1) ? (NB - 1) : b;
}
__device__ __forceinline__ float smaxOf(const float* scal) {
    float Mx = scal[0], Mn = scal[1], cmx = scal[2], cmn = scal[3];
    return fmaxf(fmaxf(cmx * Mx, cmx * Mn), fmaxf(cmn * Mx, cmn * Mn));
}
__device__ __forceinline__ float rdlane(float v, int l) {
    return __uint_as_float(__builtin_amdgcn_readlane(__float_as_uint(v), l));
}
__device__ __forceinline__ int rdlanei(int v, int l) {
    return __builtin_amdgcn_readlane(v, l);
}
// Uniform-slot select from 4 per-lane registers (no runtime array indexing
// -> no scratch; compiles to cndmask chains).
__device__ __forceinline__ float self4(int s, float a0, float a1, float a2, float a3) {
    return s == 0 ? a0 : (s == 1 ? a1 : (s == 2 ? a2 : a3));
}
__device__ __forceinline__ int seli4(int s, int a0, int a1, int a2, int a3) {
    return s == 0 ? a0 : (s == 1 ? a1 : (s == 2 ? a2 : a3));
}
// Bitwise-identical bbox recompute (same expressions/order as reference decode).
__device__ __forceinline__ void decodeBox(int idx, const float* __restrict__ g0,
        const float* __restrict__ g1, const float* __restrict__ g2,
        const float* __restrict__ anch,
        float& x1, float& y1, float& x2, float& y2) {
    const float* g; int H, ar, j;
    if (idx < N0)           { g = g0; H = 48;  ar = 2; j = idx; }
    else if (idx < N0 + N1) { g = g1; H = 96;  ar = 1; j = idx - N0; }
    else                    { g = g2; H = 192; ar = 0; j = idx - N0 - N1; }
    const float* r = g + (size_t)j * 85;
    float tx = r[0], ty = r[1], tw = r[2], th = r[3];
    int cell = j / 3, a = j - cell * 3;
    int hh = cell / H, ww = cell - hh * H;   // W == H
    float xc = (tx + (float)ww) / (float)H;
    float yc = (ty + (float)hh) / (float)H;
    float bw = expf(tw) * anch[ar * 6 + a * 2];
    float bh = expf(th) * anch[ar * 6 + a * 2 + 1];
    x1 = xc - bw * 0.5f; y1 = yc - bh * 0.5f;
    x2 = xc + bw * 0.5f; y2 = yc + bh * 0.5f;
}

// One 256-thread block per 64-box tile: 4 lanes per box. Writes conf + partials.
__global__ __launch_bounds__(256) void k_decode(
        const float* __restrict__ g0, const float* __restrict__ g1,
        const float* __restrict__ g2, float* __restrict__ conf,
        float* __restrict__ part) {
    __shared__ float sm[5440];                // 64 boxes * 85 ch
    __shared__ float red[16];
    const int tid = threadIdx.x;
    const int tile = blockIdx.x;
    const float* p; int ibase, lt;
    if (tile < 108)      { p = g0; ibase = 0;       lt = tile; }
    else if (tile < 540) { p = g1; ibase = N0;      lt = tile - 108; }
    else                 { p = g2; ibase = N0 + N1; lt = tile - 540; }
    const float4* src = (const float4*)(p + (size_t)lt * 5440);   // 16B-aligned
    for (int w = tid; w < 1360; w += 256) ((float4*)sm)[w] = src[w];
    __syncthreads();

    const int b = tid >> 2, pp = tid & 3;     // 4 lanes per box, same wave
    const float* row = sm + b * 85;
    float best = row[5 + pp * 20];
    #pragma unroll
    for (int k = 1; k < 20; k++) best = fmaxf(best, row[5 + pp * 20 + k]);
    best = fmaxf(best, __shfl_xor(best, 1));  // full-box max on all 4 lanes
    best = fmaxf(best, __shfl_xor(best, 2));
    float cmx = NEGF, cmn = POSF;
    if (pp == 0) {
        float obj = row[4];
        conf[ibase + lt * 64 + b] = obj;
        cmx = obj; cmn = obj;
    }
    // block reduce {max/min box-max, max/min conf} -> plain stores (NO atomics)
    float mpmax = best, mpmin = best;
    for (int off = 32; off; off >>= 1) {
        mpmax = fmaxf(mpmax, __shfl_down(mpmax, off));
        mpmin = fminf(mpmin, __shfl_down(mpmin, off));
        cmx   = fmaxf(cmx,   __shfl_down(cmx,   off));
        cmn   = fminf(cmn,   __shfl_down(cmn,   off));
    }
    const int lane = tid & 63, wid = tid >> 6;
    if (lane == 0) {
        red[wid * 4 + 0] = mpmax; red[wid * 4 + 1] = mpmin;
        red[wid * 4 + 2] = cmx;   red[wid * 4 + 3] = cmn;
    }
    __syncthreads();
    if (tid == 0) {
        float a0 = red[0], a1 = red[1], a2 = red[2], a3 = red[3];
        for (int w = 1; w < 4; w++) {
            a0 = fmaxf(a0, red[w * 4 + 0]); a1 = fminf(a1, red[w * 4 + 1]);
            a2 = fmaxf(a2, red[w * 4 + 2]); a3 = fminf(a3, red[w * 4 + 3]);
        }
        part[tile * 4 + 0] = a0; part[tile * 4 + 1] = a1;
        part[tile * 4 + 2] = a2; part[tile * 4 + 3] = a3;
    }
}

__global__ __launch_bounds__(256) void k_reduce(const float* __restrict__ part,
                                                float* __restrict__ scal) {
    __shared__ float red[16];
    const int tid = threadIdx.x;
    float a0 = NEGF, a1 = POSF, a2 = NEGF, a3 = POSF;
    for (int b = tid; b < NTILE; b += 256) {
        float4 p4 = ((const float4*)part)[b];
        a0 = fmaxf(a0, p4.x); a1 = fminf(a1, p4.y);
        a2 = fmaxf(a2, p4.z); a3 = fminf(a3, p4.w);
    }
    for (int off = 32; off; off >>= 1) {
        a0 = fmaxf(a0, __shfl_down(a0, off)); a1 = fminf(a1, __shfl_down(a1, off));
        a2 = fmaxf(a2, __shfl_down(a2, off)); a3 = fminf(a3, __shfl_down(a3, off));
    }
    const int lane = tid & 63, wid = tid >> 6;
    if (lane == 0) {
        red[wid * 4 + 0] = a0; red[wid * 4 + 1] = a1;
        red[wid * 4 + 2] = a2; red[wid * 4 + 3] = a3;
    }
    __syncthreads();
    if (tid == 0) {
        for (int w = 1; w < 4; w++) {
            a0 = fmaxf(a0, red[w * 4 + 0]); a1 = fminf(a1, red[w * 4 + 1]);
            a2 = fmaxf(a2, red[w * 4 + 2]); a3 = fminf(a3, red[w * 4 + 3]);
        }
        scal[0] = a0; scal[1] = a1; scal[2] = a2; scal[3] = a3;
    }
}

__global__ __launch_bounds__(256) void k_hist(const float* __restrict__ conf,
                                              const float* __restrict__ scal,
                                              int* __restrict__ hist) {
    int i = blockIdx.x * 256 + threadIdx.x;   // grid == NTOT/256 exactly
    float Mx = scal[0], Mn = scal[1];
    float Smax = smaxOf(scal);
    float c = conf[i];
    float s = fmaxf(c * Mx, c * Mn);          // == max_j conf_i * maxprob_j
    if (s > 0.0f && Smax > 0.0f)              // 8-way sharded to spread lines
        atomicAdd(&hist[((blockIdx.x & 7) << 12) + binOf(s, Smax)], 1);
}

__global__ __launch_bounds__(1024) void k_thresh(const int* __restrict__ hist,
                                                 int* __restrict__ suf,
                                                 int* __restrict__ meta) {
    __shared__ int grp[1024];
    const int tid = threadIdx.x;
    int b0 = tid * 4;
    int h[4];
    #pragma unroll
    for (int q = 0; q < 4; q++) {             // sum the 8 shards
        int s = 0;
        #pragma unroll
        for (int sh = 0; sh < 8; sh++) s += hist[sh * NB + b0 + q];
        h[q] = s;
    }
    grp[tid] = h[0] + h[1] + h[2] + h[3];
    __syncthreads();
    for (int d = 1; d < 1024; d <<= 1) {      // Hillis-Steele suffix scan
        int add = (tid + d < 1024) ? grp[tid + d] : 0;
        __syncthreads();
        grp[tid] += add;
        __syncthreads();
    }
    int gnext = (tid + 1 < 1024) ? grp[tid + 1] : 0;
    suf[b0 + 3] = gnext + h[3];
    suf[b0 + 2] = gnext + h[3] + h[2];
    suf[b0 + 1] = gnext + h[3] + h[2] + h[1];
    suf[b0 + 0] = gnext + h[3] + h[2] + h[1] + h[0];
    if (tid == 0) suf[NB] = 0;
    __syncthreads();
    if (tid == 0) {                           // min lo with suffix count <= CAP
        int L = 0, R = NB - 1, res = NB - 1;
        while (L <= R) {
            int m = (L + R) >> 1;
            if (suf[m] <= CAP) { res = m; R = m - 1; } else L = m + 1;
        }
        meta[0] = res;
    }
}

__global__ __launch_bounds__(256) void k_compact(
        const float* __restrict__ conf, const float* __restrict__ scal,
        const int* __restrict__ suf, const int* __restrict__ meta,
        int* __restrict__ binCtr, unsigned long long* __restrict__ cand) {
    int i = blockIdx.x * 256 + threadIdx.x;
    float Mx = scal[0], Mn = scal[1];
    float Smax = smaxOf(scal);
    float c = conf[i];
    float s = fmaxf(c * Mx, c * Mn);
    int lo = meta[0];
    if (s > 0.0f && Smax > 0.0f) {
        int b = binOf(s, Smax);
        if (b >= lo) {
            // exact position: (#cands in higher bins) + rank within bin
            int pos = suf[b + 1] + atomicAdd(&binCtr[b], 1);
            if (pos < CAP)
                // key: score bits | ~idx (ties: smallest idx first in desc sort)
                cand[pos] = ((unsigned long long)__float_as_uint(s) << 32)
                          | (unsigned long long)(~(unsigned)i);
        }
    }
}

// 256 threads (4 waves). Consumes cand[] (bin-descending order) in bin-aligned
// chunks. Rank sort + parallel pre-test; serial greedy accept on wave 0 with
// 4 register-resident candidates per lane.
__global__ __launch_bounds__(TBLK) void k_nms(
        const float* __restrict__ g0, const float* __restrict__ g1,
        const float* __restrict__ g2, const float* __restrict__ anch,
        const float* __restrict__ conf, const float* __restrict__ scal,
        const int* __restrict__ suf, const int* __restrict__ meta,
        const unsigned long long* __restrict__ cand, float* __restrict__ out) {
    __shared__ unsigned long long keys[CAPL]; // 16 KB
    __shared__ float4 boxI[TBLK];             // candidate tile (decoded)
    __shared__ float  areaI[TBLK], scoreI[TBLK];
    __shared__ int    idxI[TBLK], aliveI[TBLK];
    __shared__ float4 selBox[MAXB];
    __shared__ float  selA[MAXB], selS[MAXB];
    __shared__ int    selIdx[MAXB];
    __shared__ int    sh_cnt, sh_nsel;

    const int tid = threadIdx.x;
    const int lane = tid & 63, wid = tid >> 6;
    const float Mx = scal[0], Mn = scal[1];
    const float Smax = smaxOf(scal);
    const int loGlob = meta[0];
    int nsel = 0;
    int hi = NB;

    while (nsel < MAXB && hi > 0) {
        const bool fast = hi > loGlob;        // cand[] covers bins >= loGlob
        const int sufHi = suf[hi];
        int l;
        {   // min l in [lb, hi) with chunk count <= cap (single over-full bin ok)
            int lb = fast ? loGlob : 0;
            int capHere = fast ? CHUNK : CAPL;
            int L = lb, R = hi - 1, res = hi - 1;
            while (L <= R) {
                int m = (L + R) >> 1;
                if (suf[m] - sufHi <= capHere) { res = m; R = m - 1; } else L = m + 1;
            }
            l = res;                          // l < hi: guaranteed progress
        }
        int cnt;
        if (fast) {
            cnt = suf[l] - sufHi;
            for (int i = tid; i < cnt; i += TBLK) keys[i] = cand[sufHi + i];
            __syncthreads();
        } else {                              // exact fallback (cold path)
            if (tid == 0) sh_cnt = 0;
            __syncthreads();
            for (int i = tid; i < NTOT; i += TBLK) {
                float c = conf[i];
                float s = fmaxf(c * Mx, c * Mn);
                if (s > 0.0f) {
                    int b = binOf(s, Smax);
                    if (b >= l && b < hi) {
                        int pos = atomicAdd(&sh_cnt, 1);
                        if (pos < CAPL)
                            keys[pos] = ((unsigned long long)__float_as_uint(s) << 32)
                                      | (unsigned long long)(~(unsigned)i);
                    }
                }
            }
            __syncthreads();
            cnt = sh_cnt; if (cnt > CAPL) cnt = CAPL;
        }
        if (cnt > 0) {
            // ---- rank sort (keys unique -> ranks unique), in-place permute ----
            if (cnt <= TBLK) {
                unsigned long long mk = (tid < cnt) ? keys[tid] : 0ULL;
                int rank = 0;
                #pragma unroll 8
                for (int j = 0; j < cnt; j++) rank += (keys[j] > mk) ? 1 : 0;
                __syncthreads();
                if (tid < cnt) keys[rank] = mk;
                __syncthreads();
            } else {                          // up to CAPL = 8 keys/thread
                unsigned long long mk[8]; int rk[8];
                #pragma unroll
                for (int q = 0; q < 8; q++) {
                    int ii = tid + (q << 8);
                    mk[q] = (ii < cnt) ? keys[ii] : 0ULL;
                    rk[q] = 0;
                }
                for (int j = 0; j < cnt; j++) {
                    unsigned long long kj = keys[j];
                    #pragma unroll
                    for (int q = 0; q < 8; q++) rk[q] += (kj > mk[q]) ? 1 : 0;
                }
                __syncthreads();
                #pragma unroll
                for (int q = 0; q < 8; q++) {
                    int ii = tid + (q << 8);
                    if (ii < cnt) keys[rk[q]] = mk[q];
                }
                __syncthreads();
            }
            // ---- sweep in 256-candidate tiles ----
            for (int t0 = 0; t0 < cnt && nsel < MAXB; t0 += TBLK) {
                int tcnt = cnt - t0; if (tcnt > TBLK) tcnt = TBLK;
                float x1 = 0.f, y1 = 0.f, x2 = 0.f, y2 = 0.f, ar = 0.f, sc = 0.f;
                int idx = 0, alive = 0;
                if (tid < tcnt) {
                    unsigned long long key = keys[t0 + tid];
                    idx = (int)(~(unsigned)key);
                    sc = __uint_as_float((unsigned)(key >> 32));
                    decodeBox(idx, g0, g1, g2, anch, x1, y1, x2, y2);
                    ar = (x2 - x1) * (y2 - y1);
                    alive = 1;
                    for (int s2 = 0; s2 < nsel; s2++) {   // vs prior selections
                        float4 sb = selBox[s2];
                        float sa = selA[s2];
                        float iw = fminf(x2, sb.z) - fmaxf(x1, sb.x);
                        float ih = fminf(y2, sb.w) - fmaxf(y1, sb.y);
                        iw = fmaxf(iw, 0.f); ih = fmaxf(ih, 0.f);
                        float inter = iw * ih;
                        if (inter / (ar + sa - inter) > 0.5f) { alive = 0; break; }
                    }
                }
                boxI[tid] = make_float4(x1, y1, x2, y2);
                areaI[tid] = ar; scoreI[tid] = sc; idxI[tid] = idx; aliveI[tid] = alive;
                __syncthreads();
                if (wid == 0) {               // serial greedy on wave 0
                    float cx1[4], cy1[4], cx2[4], cy2[4], car[4], csc[4];
                    int cid[4], am = 0;
                    #pragma unroll
                    for (int q = 0; q < 4; q++) {
                        int ci = (lane << 2) + q;
                        float4 b = boxI[ci];
                        cx1[q] = b.x; cy1[q] = b.y; cx2[q] = b.z; cy2[q] = b.w;
                        car[q] = areaI[ci]; csc[q] = scoreI[ci]; cid[q] = idxI[ci];
                        am |= aliveI[ci] << q;
                    }
                    while (nsel < MAXB) {
                        unsigned long long bal = __ballot(am != 0);
                        if (!bal) break;
                        int w = __ffsll(bal) - 1;             // first alive lane
                        int slot = __ffs(rdlanei(am, w)) - 1; // its first alive slot
                        float wx1 = rdlane(self4(slot, cx1[0], cx1[1], cx1[2], cx1[3]), w);
                        float wy1 = rdlane(self4(slot, cy1[0], cy1[1], cy1[2], cy1[3]), w);
                        float wx2 = rdlane(self4(slot, cx2[0], cx2[1], cx2[2], cx2[3]), w);
                        float wy2 = rdlane(self4(slot, cy2[0], cy2[1], cy2[2], cy2[3]), w);
                        float wa  = rdlane(self4(slot, car[0], car[1], car[2], car[3]), w);
                        float ws  = rdlane(self4(slot, csc[0], csc[1], csc[2], csc[3]), w);
                        int   wi  = rdlanei(seli4(slot, cid[0], cid[1], cid[2], cid[3]), w);
                        if (lane == 0) {
                            selBox[nsel] = make_float4(wx1, wy1, wx2, wy2);
                            selA[nsel] = wa; selS[nsel] = ws; selIdx[nsel] = wi;
                        }
                        // kill: each lane tests its 4 boxes vs winner.
                        // Winner kills itself via IoU=1 (NaN => stays alive,
                        // re-selected — matches reference scan exactly).
                        #pragma unroll
                        for (int q = 0; q < 4; q++) {
                            float iw = fminf(cx2[q], wx2) - fmaxf(cx1[q], wx1);
                            float ih = fminf(cy2[q], wy2) - fmaxf(cy1[q], wy1);
                            iw = fmaxf(iw, 0.f); ih = fmaxf(ih, 0.f);
                            float inter = iw * ih;
                            if (inter / (car[q] + wa - inter) > 0.5f) am &= ~(1 << q);
                        }
                        nsel++;
                    }
                    if (lane == 0) sh_nsel = nsel;
                }
                __syncthreads();
                nsel = sh_nsel;               // uniform across all 4 waves
            }
        }
        hi = l;
    }
    __syncthreads();

    // outputs: boxes[100*4] | scores[100] | classes[100] | num_valid (all fp32)
    for (int k = tid; k < MAXB; k += TBLK) {
        float b0 = 0.f, b1 = 0.f, b2 = 0.f, b3 = 0.f, sv = 0.f, cv = 0.f;
        if (k < nsel) {
            float4 sb = selBox[k];
            b0 = sb.x; b1 = sb.y; b2 = sb.z; b3 = sb.w;
            sv = selS[k];
            int idx = selIdx[k];              // class argmax only for selected
            const float* g; int j;
            if (idx < N0)           { g = g0; j = idx; }
            else if (idx < N0 + N1) { g = g1; j = idx - N0; }
            else                    { g = g2; j = idx - N0 - N1; }
            const float* r = g + (size_t)j * 85 + 5;
            float v[NCLS];
            #pragma unroll                    // all 80 loads in flight, one wait
            for (int q = 0; q < NCLS; q++) v[q] = r[q];
            float best = v[0]; int c = 0;
            #pragma unroll
            for (int q = 1; q < NCLS; q++)
                if (v[q] > best) { best = v[q]; c = q; }   // strict > = first max
            cv = (float)c;
        }
        out[4 * k + 0] = b0; out[4 * k + 1] = b1;
        out[4 * k + 2] = b2; out[4 * k + 3] = b3;
        out[400 + k] = sv;
        out[500 + k] = cv;
    }
    if (tid == 0) out[600] = (float)nsel;
}

extern "C" void kernel_launch(void* const* d_in, const int* in_sizes, int n_in,
                              void* d_out, int out_size, void* d_ws, size_t ws_size,
                              hipStream_t stream) {
    const float* g0   = (const float*)d_in[0];
    const float* g1   = (const float*)d_in[1];
    const float* g2   = (const float*)d_in[2];
    const float* anch = (const float*)d_in[3];
    char* ws = (char*)d_ws;
    float* conf  = (float*)(ws + WS_CONF);
    float* scal  = (float*)(ws + WS_SCAL);
    float* part  = (float*)(ws + WS_PART);
    int*   hist  = (int*)(ws + WS_HIST);
    int*   binc  = (int*)(ws + WS_BINC);
    int*   suf   = (int*)(ws + WS_SUF);
    int*   meta  = (int*)(ws + WS_META);
    unsigned long long* cand = (unsigned long long*)(ws + WS_CAND);
    float* out   = (float*)d_out;

    hipMemsetAsync(ws + WS_HIST, 0, 9 * NB * 4, stream);    // hist shards + binCtr
    k_decode <<<NTILE, 256, 0, stream>>>(g0, g1, g2, conf, part);
    k_reduce <<<1, 256, 0, stream>>>(part, scal);
    k_hist   <<<NTOT / 256, 256, 0, stream>>>(conf, scal, hist);
    k_thresh <<<1, 1024, 0, stream>>>(hist, suf, meta);
    k_compact<<<NTOT / 256, 256, 0, stream>>>(conf, scal, suf, meta, binc, cand);
    k_nms    <<<1, TBLK, 0, stream>>>(g0, g1, g2, anch, conf, scal, suf, meta, cand, out);
}